// Round 1
// 656.518 us; speedup vs baseline: 1.2290x; 1.2290x over previous
//
#include <hip/hip_runtime.h>

typedef unsigned short u16;
typedef __attribute__((ext_vector_type(8))) __bf16 bf16x8;
typedef __attribute__((ext_vector_type(8))) short short8;
typedef __attribute__((ext_vector_type(4))) float f32x4;

#define NE 8            // experts

__device__ __forceinline__ u16 f2bf(float f) {
    union { float f; unsigned u; } v; v.f = f;
    unsigned u = v.u;
    return (u16)((u + 0x7fffu + ((u >> 16) & 1u)) >> 16);
}

__device__ __forceinline__ f32x4 mfma16(short8 a, short8 b, f32x4 c) {
    return __builtin_amdgcn_mfma_f32_16x16x32_bf16(
        __builtin_bit_cast(bf16x8, a), __builtin_bit_cast(bf16x8, b), c, 0, 0, 0);
}

// async global->LDS, 16B per lane; lds dest = wave-uniform base + lane*16
__device__ __forceinline__ void gl2lds(const u16* g, u16* l) {
    __builtin_amdgcn_global_load_lds((const __attribute__((address_space(1))) void*)g,
                                     (__attribute__((address_space(3))) void*)l,
                                     16, 0, 0);
}

// ---------------- w2 fp32 -> bf16 (grid-stride, float4) ----------------
__global__ void cvt_kernel(const float* __restrict__ in, u16* __restrict__ out, size_t n4) {
    size_t i = (size_t)blockIdx.x * blockDim.x + threadIdx.x;
    size_t stride = (size_t)gridDim.x * blockDim.x;
    for (; i < n4; i += stride) {
        float4 v = ((const float4*)in)[i];
        ushort4 o;
        o.x = f2bf(v.x); o.y = f2bf(v.y); o.z = f2bf(v.z); o.w = f2bf(v.w);
        ((ushort4*)out)[i] = o;
    }
}

// ---- w1/w3 -> bf16 wc[e][2H][D], 16-row interleave:
//      H-col j -> w1 at wc row (j>>4)*32 + (j&15); w3 at +16.
__global__ void cvt_w13_kernel(const float* __restrict__ w1, const float* __restrict__ w3,
                               u16* __restrict__ wc, int H, int D) {
    size_t n = (size_t)NE * H * (D / 4);
    size_t i = (size_t)blockIdx.x * blockDim.x + threadIdx.x;
    size_t stride = (size_t)gridDim.x * blockDim.x;
    int d4n = D / 4;
    for (; i < n; i += stride) {
        int d4 = (int)(i % d4n);
        size_t rem = i / d4n;
        int j = (int)(rem % H);
        int e = (int)(rem / H);
        float4 v1 = ((const float4*)w1)[i];
        float4 v3 = ((const float4*)w3)[i];
        ushort4 o1, o3;
        o1.x = f2bf(v1.x); o1.y = f2bf(v1.y); o1.z = f2bf(v1.z); o1.w = f2bf(v1.w);
        o3.x = f2bf(v3.x); o3.y = f2bf(v3.y); o3.z = f2bf(v3.z); o3.w = f2bf(v3.w);
        int wcrow = ((j >> 4) << 5) + (j & 15);
        size_t o = (((size_t)e * 2 * H + wcrow) * d4n + d4);
        ((ushort4*)wc)[o] = o1;
        ((ushort4*)wc)[o + (size_t)16 * d4n] = o3;
    }
}

// ---------------- router: noisy top-2 gating + x->bf16, one wave per token ----------------
// NO atomics: writes per-token packed top-2 indices + gates; build_kernel compacts.
__global__ void router_kernel(const float* __restrict__ x, const float* __restrict__ noise,
                              const float* __restrict__ rw, const float* __restrict__ rb,
                              const float* __restrict__ nw, const float* __restrict__ nb,
                              int* __restrict__ tops, float* __restrict__ gpair,
                              u16* __restrict__ xb, int T, int D) {
    int wv = threadIdx.x >> 6;
    int lane = threadIdx.x & 63;
    int t = blockIdx.x * 4 + wv;
    if (t >= T) return;

    const float4* x4 = (const float4*)(x + (size_t)t * D) + lane * 4;
    float4 xv0 = x4[0], xv1 = x4[1], xv2 = x4[2], xv3 = x4[3];

    {
        ushort4 s0, s1, s2, s3;
        s0.x = f2bf(xv0.x); s0.y = f2bf(xv0.y); s0.z = f2bf(xv0.z); s0.w = f2bf(xv0.w);
        s1.x = f2bf(xv1.x); s1.y = f2bf(xv1.y); s1.z = f2bf(xv1.z); s1.w = f2bf(xv1.w);
        s2.x = f2bf(xv2.x); s2.y = f2bf(xv2.y); s2.z = f2bf(xv2.z); s2.w = f2bf(xv2.w);
        s3.x = f2bf(xv3.x); s3.y = f2bf(xv3.y); s3.z = f2bf(xv3.z); s3.w = f2bf(xv3.w);
        ushort4* o = (ushort4*)(xb + (size_t)t * D + lane * 16);
        o[0] = s0; o[1] = s1; o[2] = s2; o[3] = s3;
    }

    // 16 partial dot-products per lane, then ONE batched 6-stage butterfly
    // (depth 6 instead of 16 serial 6-stage reductions).
    float acc[2 * NE];
#pragma unroll
    for (int e = 0; e < NE; e++) {
        const float4* w4 = (const float4*)(rw + (size_t)e * D) + lane * 4;
        float4 a = w4[0], b = w4[1], c = w4[2], d = w4[3];
        acc[e] = xv0.x*a.x + xv0.y*a.y + xv0.z*a.z + xv0.w*a.w
               + xv1.x*b.x + xv1.y*b.y + xv1.z*b.z + xv1.w*b.w
               + xv2.x*c.x + xv2.y*c.y + xv2.z*c.z + xv2.w*c.w
               + xv3.x*d.x + xv3.y*d.y + xv3.z*d.z + xv3.w*d.w;
        const float4* v4 = (const float4*)(nw + (size_t)e * D) + lane * 4;
        a = v4[0]; b = v4[1]; c = v4[2]; d = v4[3];
        acc[NE + e] = xv0.x*a.x + xv0.y*a.y + xv0.z*a.z + xv0.w*a.w
                    + xv1.x*b.x + xv1.y*b.y + xv1.z*b.z + xv1.w*b.w
                    + xv2.x*c.x + xv2.y*c.y + xv2.z*c.z + xv2.w*c.w
                    + xv3.x*d.x + xv3.y*d.y + xv3.z*d.z + xv3.w*d.w;
    }
#pragma unroll
    for (int m = 1; m < 64; m <<= 1) {
#pragma unroll
        for (int k = 0; k < 2 * NE; k++) acc[k] += __shfl_xor(acc[k], m);
    }

    if (lane == 0) {
        float v0 = -1e30f, v1 = -1e30f;
        int i0 = 0, i1 = 0;
#pragma unroll
        for (int e = 0; e < NE; e++) {
            float z = acc[NE + e] + nb[e];
            float sp = (z > 20.f) ? z : log1pf(expf(z));
            float nv = acc[e] + rb[e] + noise[(size_t)t * NE + e] * sp;
            if (nv > v0) { v1 = v0; i1 = i0; v0 = nv; i0 = e; }
            else if (nv > v1) { v1 = nv; i1 = e; }
        }
        float e1 = expf(v1 - v0);
        float inv = 1.f / (1.f + e1);
        tops[t] = i0 | (i1 << 8);
        gpair[2 * t]     = inv;
        gpair[2 * t + 1] = e1 * inv;
    }
}

// ---------------- build: deterministic per-expert compaction (no atomics) ----------------
// One block per expert; block-wide prefix sums over token order.
__global__ void build_kernel(const int* __restrict__ tops, const float* __restrict__ gpair,
                             int* __restrict__ counts, int* __restrict__ list,
                             float* __restrict__ glist, int* __restrict__ tokslot, int T) {
    int e = blockIdx.x;
    int tid = threadIdx.x, lane = tid & 63, wv = tid >> 6;
    __shared__ int wsum[4];
    __shared__ int sbase;
    if (tid == 0) sbase = 0;
    __syncthreads();
    for (int t0 = 0; t0 < T; t0 += 256) {
        int t = t0 + tid;
        int pk = tops[t];
        int i0 = pk & 0xff, i1 = (pk >> 8) & 0xff;
        bool f0 = (i0 == e), f1 = (i1 == e);
        bool f = f0 || f1;
        unsigned long long m = __ballot(f);
        int lpos = __popcll(m & (((unsigned long long)1 << lane) - 1ull));
        if (lane == 0) wsum[wv] = __popcll(m);
        __syncthreads();
        int woff = sbase;
        for (int w = 0; w < wv; w++) woff += wsum[w];
        int tot = wsum[0] + wsum[1] + wsum[2] + wsum[3];
        if (f) {
            int pos = woff + lpos;
            list[e * T + pos]  = t;
            glist[e * T + pos] = f0 ? gpair[2 * t] : gpair[2 * t + 1];
            tokslot[2 * t + (f0 ? 0 : 1)] = (e << 16) | pos;
        }
        __syncthreads();
        if (tid == 0) sbase += tot;
    }
    __syncthreads();
    if (tid == 0) counts[e] = sbase;
}

// ---------------- scan + compact block map: bmap[b] = (e<<16)|mblk ----------------
__global__ void scan_kernel(const int* __restrict__ counts, int* __restrict__ offsets,
                            int* __restrict__ bmap, int* __restrict__ nb) {
    if (threadIdx.x == 0 && blockIdx.x == 0) {
        int s = 0, t = 0;
        for (int e = 0; e < NE; e++) {
            offsets[e] = s;
            int c = counts[e];
            s += c;
            int m = (c + 127) >> 7;
            for (int i = 0; i < m; i++) bmap[t++] = (e << 16) | i;
        }
        offsets[NE] = s;
        nb[0] = t;
    }
}

// ---------------- GEMM1: xb(gathered) @ wc^T; epilogue silu(h1)*h3*gate -> hb ----------------
// grid (nblk=32, tile); dbuf LDS; 16-row-interleaved wc -> shfl-free epilogue.
__launch_bounds__(256)
__global__ void gemm1_kernel(const u16* __restrict__ xb, const u16* __restrict__ wc,
                             const int* __restrict__ counts, const int* __restrict__ offsets,
                             const int* __restrict__ list, const float* __restrict__ glist,
                             const int* __restrict__ bmap, const int* __restrict__ nb,
                             u16* __restrict__ hb, int T, int D, int H) {
    if ((int)blockIdx.y >= nb[0]) return;
    int info = bmap[blockIdx.y];
    int e = info >> 16, mblk = info & 0xffff, nblk = blockIdx.x;
    int count = counts[e];

    __shared__ u16 sA[2 * 4096];
    __shared__ u16 sB[2 * 4096];
    __shared__ int stok[128];
    __shared__ float sgate[128];

    int tid = threadIdx.x;
    int lane = tid & 63, wvi = tid >> 6;

    if (tid < 128) {
        int rr = min(mblk * 128 + tid, count - 1);
        stok[tid]  = list[e * T + rr];
        sgate[tid] = glist[e * T + rr];
    }
    __syncthreads();

    int n0 = nblk * 128;
    const u16* wcp = wc + ((size_t)e * 2 * H + n0) * D;

    int rowc = tid >> 2, col8 = (tid & 3) * 8;
    const u16* pa0 = xb + (size_t)stok[rowc] * D + col8;
    const u16* pa1 = xb + (size_t)stok[64 + rowc] * D + col8;
    const u16* pb0 = wcp + (size_t)rowc * D + col8;
    const u16* pb1 = wcp + (size_t)(64 + rowc) * D + col8;
    int lo0 = wvi * 512, lo1 = 2048 + wvi * 512;

    f32x4 acc[4][4];
#pragma unroll
    for (int mi = 0; mi < 4; mi++)
#pragma unroll
        for (int ni = 0; ni < 4; ni++) acc[mi][ni] = (f32x4)0.f;

    int wm = (wvi & 1) * 64, wn = (wvi >> 1) * 64;
    int r = lane & 15, q = lane >> 4;

#define G1_ISSUE(buf) do { \
        gl2lds(pa0, sA + (buf) * 4096 + lo0); gl2lds(pa1, sA + (buf) * 4096 + lo1); \
        gl2lds(pb0, sB + (buf) * 4096 + lo0); gl2lds(pb1, sB + (buf) * 4096 + lo1); \
        pa0 += 32; pa1 += 32; pb0 += 32; pb1 += 32; } while (0)

#define G1_COMPUTE(buf) do { \
        short8 a[4], b[4]; \
        _Pragma("unroll") \
        for (int mi = 0; mi < 4; mi++) \
            a[mi] = *(const short8*)(&sA[(buf) * 4096 + (wm + mi * 16 + r) * 32 + q * 8]); \
        _Pragma("unroll") \
        for (int ni = 0; ni < 4; ni++) \
            b[ni] = *(const short8*)(&sB[(buf) * 4096 + (wn + ni * 16 + r) * 32 + q * 8]); \
        _Pragma("unroll") \
        for (int mi = 0; mi < 4; mi++) \
            _Pragma("unroll") \
            for (int ni = 0; ni < 4; ni++) \
                acc[mi][ni] = mfma16(a[mi], b[ni], acc[mi][ni]); } while (0)

    G1_ISSUE(0);
    for (int k0 = 0; k0 < D; k0 += 64) {
        __syncthreads();
        if (k0 + 32 < D) G1_ISSUE(1);
        G1_COMPUTE(0);
        __syncthreads();
        if (k0 + 64 < D) G1_ISSUE(0);
        G1_COMPUTE(1);
    }

    // epilogue: acc[mi][2g] = h1, acc[mi][2g+1] = h3 of the same H-column (same lane).
    int hrow0 = offsets[e];
#pragma unroll
    for (int mi = 0; mi < 4; mi++) {
#pragma unroll
        for (int g = 0; g < 2; g++) {
            int col = nblk * 64 + (wn >> 1) + g * 16 + r;
#pragma unroll
            for (int tt = 0; tt < 4; tt++) {
                int lrow = wm + mi * 16 + q * 4 + tt;
                int grow = mblk * 128 + lrow;
                if (grow < count) {
                    float v = acc[mi][2 * g][tt];
                    float hv = v / (1.f + expf(-v)) * acc[mi][2 * g + 1][tt] * sgate[lrow];
                    hb[(size_t)(hrow0 + grow) * H + col] = f2bf(hv);
                }
            }
        }
    }
}

// ---------------- GEMM2: o2[row] = h[row] @ w2^T (packed, coalesced stores) ----------------
__launch_bounds__(256)
__global__ void gemm2_kernel(const u16* __restrict__ hb, const u16* __restrict__ w2b,
                             const int* __restrict__ counts, const int* __restrict__ offsets,
                             const int* __restrict__ bmap, const int* __restrict__ nb,
                             float* __restrict__ o2, int T, int D, int H) {
    if ((int)blockIdx.y >= nb[0]) return;
    int info = bmap[blockIdx.y];
    int e = info >> 16, mblk = info & 0xffff, nblk = blockIdx.x;
    int count = counts[e];

    __shared__ u16 sA[2 * 4096];
    __shared__ u16 sB[2 * 4096];

    int tid = threadIdx.x;
    int lane = tid & 63, wvi = tid >> 6;
    int off0 = offsets[e];
    int n0 = nblk * 128;
    const u16* w2p = w2b + ((size_t)e * D + n0) * H;

    int rowc = tid >> 2, col8 = (tid & 3) * 8;
    int ra0 = min(mblk * 128 + rowc, count - 1);
    int ra1 = min(mblk * 128 + 64 + rowc, count - 1);
    const u16* pa0 = hb + (size_t)(off0 + ra0) * H + col8;
    const u16* pa1 = hb + (size_t)(off0 + ra1) * H + col8;
    const u16* pb0 = w2p + (size_t)rowc * H + col8;
    const u16* pb1 = w2p + (size_t)(64 + rowc) * H + col8;
    int lo0 = wvi * 512, lo1 = 2048 + wvi * 512;

    f32x4 acc[4][4];
#pragma unroll
    for (int mi = 0; mi < 4; mi++)
#pragma unroll
        for (int ni = 0; ni < 4; ni++) acc[mi][ni] = (f32x4)0.f;

    int wm = (wvi & 1) * 64, wn = (wvi >> 1) * 64;
    int r = lane & 15, q = lane >> 4;

#define G2_ISSUE(buf) do { \
        gl2lds(pa0, sA + (buf) * 4096 + lo0); gl2lds(pa1, sA + (buf) * 4096 + lo1); \
        gl2lds(pb0, sB + (buf) * 4096 + lo0); gl2lds(pb1, sB + (buf) * 4096 + lo1); \
        pa0 += 32; pa1 += 32; pb0 += 32; pb1 += 32; } while (0)

#define G2_COMPUTE(buf) do { \
        short8 a[4], b[4]; \
        _Pragma("unroll") \
        for (int mi = 0; mi < 4; mi++) \
            a[mi] = *(const short8*)(&sA[(buf) * 4096 + (wm + mi * 16 + r) * 32 + q * 8]); \
        _Pragma("unroll") \
        for (int ni = 0; ni < 4; ni++) \
            b[ni] = *(const short8*)(&sB[(buf) * 4096 + (wn + ni * 16 + r) * 32 + q * 8]); \
        _Pragma("unroll") \
        for (int mi = 0; mi < 4; mi++) \
            _Pragma("unroll") \
            for (int ni = 0; ni < 4; ni++) \
                acc[mi][ni] = mfma16(a[mi], b[ni], acc[mi][ni]); } while (0)

    G2_ISSUE(0);
    for (int k0 = 0; k0 < H; k0 += 64) {
        __syncthreads();
        if (k0 + 32 < H) G2_ISSUE(1);
        G2_COMPUTE(0);
        __syncthreads();
        if (k0 + 64 < H) G2_ISSUE(0);
        G2_COMPUTE(1);
    }

    // epilogue: coalesced packed stores (no atomics)
#pragma unroll
    for (int mi = 0; mi < 4; mi++) {
#pragma unroll
        for (int tt = 0; tt < 4; tt++) {
            int grow = mblk * 128 + wm + mi * 16 + q * 4 + tt;
            if (grow < count) {
#pragma unroll
                for (int ni = 0; ni < 4; ni++) {
                    int col = n0 + wn + ni * 16 + r;
                    o2[(size_t)(off0 + grow) * D + col] = acc[mi][ni][tt];
                }
            }
        }
    }
}

// ---------------- combine: out[t] = o2[row0(t)] + o2[row1(t)] ----------------
__global__ void combine_kernel(const float* __restrict__ o2, const int* __restrict__ tokslot,
                               const int* __restrict__ offsets, float* __restrict__ out, int D) {
    int t = blockIdx.x;
    int s0 = tokslot[2 * t], s1 = tokslot[2 * t + 1];
    size_t r0 = offsets[s0 >> 16] + (s0 & 0xffff);
    size_t r1 = offsets[s1 >> 16] + (s1 & 0xffff);
    int c = threadIdx.x * 4;
    float4 a = *(const float4*)(o2 + r0 * D + c);
    float4 b = *(const float4*)(o2 + r1 * D + c);
    float4 o; o.x = a.x + b.x; o.y = a.y + b.y; o.z = a.z + b.z; o.w = a.w + b.w;
    *(float4*)(out + (size_t)t * D + c) = o;
}

extern "C" void kernel_launch(void* const* d_in, const int* in_sizes, int n_in,
                              void* d_out, int out_size, void* d_ws, size_t ws_size,
                              hipStream_t stream) {
    const float* x     = (const float*)d_in[0];
    const float* noise = (const float*)d_in[1];
    const float* rw    = (const float*)d_in[2];
    const float* rb    = (const float*)d_in[3];
    const float* nw    = (const float*)d_in[4];
    const float* nb_   = (const float*)d_in[5];
    const float* w1    = (const float*)d_in[6];
    const float* w2    = (const float*)d_in[7];
    const float* w3    = (const float*)d_in[8];
    float* out = (float*)d_out;

    const int E = NE;
    const int D = in_sizes[2] / E;              // 1024
    const int T = in_sizes[0] / D;              // 8192
    const int H = in_sizes[6] / (E * D);        // 2048

    auto al = [](size_t v) { return (v + 255) & ~(size_t)255; };
    char* p = (char*)d_ws;
    size_t o_counts  = 0;                                     // 8 ints
    size_t o_offsets = 64;                                    // 9 ints
    size_t o_nb      = 128;                                   // 1 int
    size_t o_bmap    = 256;                                   // up to 2T/128+NE ints
    size_t o_tslot   = al(o_bmap  + 2048);
    size_t o_list    = al(o_tslot + (size_t)2 * T * 4);
    size_t o_glist   = al(o_list  + (size_t)E * T * 4);
    size_t o_xb      = al(o_glist + (size_t)E * T * 4);
    size_t o_wc      = al(o_xb    + (size_t)T * D * 2);       // wc reused as o2 after gemm1
    size_t o_w2b     = al(o_wc    + (size_t)E * 2 * H * D * 2);
    size_t o_hb      = al(o_w2b   + (size_t)E * D * H * 2);

    int*   counts  = (int*)(p + o_counts);
    int*   offsets = (int*)(p + o_offsets);
    int*   nblk    = (int*)(p + o_nb);
    int*   bmap    = (int*)(p + o_bmap);
    int*   tokslot = (int*)(p + o_tslot);
    int*   list    = (int*)(p + o_list);
    float* glist   = (float*)(p + o_glist);
    u16*   xb      = (u16*)(p + o_xb);
    u16*   wc      = (u16*)(p + o_wc);
    float* o2      = (float*)(p + o_wc);        // overlay: wc dead after gemm1
    u16*   w2b     = (u16*)(p + o_w2b);
    u16*   hb      = (u16*)(p + o_hb);
    // tops/gpair overlay head of hb region: dead before gemm1 writes hb.
    int*   tops    = (int*)(p + o_hb);                        // T ints   (32 KB)
    float* gpair   = (float*)(p + o_hb + (size_t)T * 4);      // 2T floats (64 KB)

    cvt_w13_kernel<<<2048, 256, 0, stream>>>(w1, w3, wc, H, D);
    cvt_kernel<<<2048, 256, 0, stream>>>(w2, w2b, (size_t)E * D * H / 4);

    router_kernel<<<(T + 3) / 4, 256, 0, stream>>>(x, noise, rw, rb, nw, nb_,
                                                   tops, gpair, xb, T, D);
    build_kernel<<<NE, 256, 0, stream>>>(tops, gpair, counts, list, glist, tokslot, T);
    scan_kernel<<<1, 64, 0, stream>>>(counts, offsets, bmap, nblk);

    int maxb = 2 * T / 128 + NE;                // 136
    dim3 g1(2 * H / 128, maxb, 1);              // nblk fast dim: A-tile reuse locality
    gemm1_kernel<<<g1, 256, 0, stream>>>(xb, wc, counts, offsets, list, glist,
                                         bmap, nblk, hb, T, D, H);
    dim3 g2(D / 128, maxb, 1);
    gemm2_kernel<<<g2, 256, 0, stream>>>(hb, w2b, counts, offsets,
                                         bmap, nblk, o2, T, D, H);
    combine_kernel<<<T, 256, 0, stream>>>(o2, tokslot, offsets, out, D);
}